// Round 3
// baseline (1208.050 us; speedup 1.0000x reference)
//
#include <hip/hip_runtime.h>
#include <math.h>

#define BT 2048

typedef __attribute__((ext_vector_type(8))) short bf16x8;
typedef __attribute__((ext_vector_type(4))) float f32x4;
typedef __attribute__((ext_vector_type(4))) unsigned short u16x4;

__device__ inline unsigned short f2bf(float f) {
    union { float f; unsigned u; } v; v.f = f;
    unsigned r = (v.u >> 16) & 1u;
    return (unsigned short)((v.u + 0x7FFFu + r) >> 16);
}
__device__ inline float bf2f(unsigned short s) {
    union { unsigned u; float f; } v; v.u = ((unsigned)s) << 16;
    return v.f;
}

__device__ inline float dot4(const float4 a, const float4 b) {
    return fmaf(a.x, b.x, fmaf(a.y, b.y, fmaf(a.z, b.z, a.w * b.w)));
}

union F8 { float4 v2[2]; float f[8]; };

// x/feats LDS planes: [64 rows][264 cols] ushort (pad 8 cols kills stride-256 conflicts)
#define XP 264

// ---------------------------------------------------------------------------
// Pre-swizzle weights into MFMA B-fragment order, SPLIT bf16 hi/lo.
__global__ __launch_bounds__(256) void k_prep(const float* __restrict__ inW,
                                              const float* __restrict__ gatW,
                                              unsigned short* __restrict__ dst) {
    int gid = blockIdx.x * 256 + threadIdx.x;   // 0..65535
    int mat = gid >> 14;
    int r   = gid & 16383;
    int ks  = r >> 10;
    int nt  = (r >> 6) & 15;
    int lane = r & 63;
    int ln15 = lane & 15, q = lane >> 4;
    int n  = nt * 16 + ln15;
    int k0 = ks * 32 + q * 8;
    const float* src; bool tr;
    if (mat == 0) { src = inW; tr = true; }
    else          { src = gatW + (size_t)(mat - 1) * 65536; tr = false; }
    unsigned short* d = dst + ((size_t)mat * 16384 + r) * 16;
    if (ks < 8) {
        #pragma unroll
        for (int j = 0; j < 8; j++) {
            float v = tr ? src[n * 256 + k0 + j] : src[(size_t)(k0 + j) * 256 + n];
            unsigned short hi = f2bf(v);
            d[j]     = hi;
            d[8 + j] = f2bf(v - bf2f(hi));
        }
    } else {
        #pragma unroll
        for (int j = 0; j < 8; j++) { d[j] = 0; d[8 + j] = 0; }
    }
}

// ---------------------------------------------------------------------------
// Fully fused GNN: in_proj + 3 GAT layers + masked frame mean.
// LDS diet: x planes and hT SHARE one 69.6 KB union (disjoint live ranges).
// The residual x_old + bias is folded into the P.H MFMA C-operand init, read
// from the union BEFORE phase C overwrites it with hT. Total LDS ~78 KB ->
// 2 blocks/CU (16 waves). __launch_bounds__(512,4) caps VGPR at 128.
__global__ __launch_bounds__(512, 4) void k_gnn(const float* __restrict__ feats,
                                                const float* __restrict__ boxes,
                                                const float* __restrict__ maskp,
                                                const unsigned short* __restrict__ BswAll,
                                                const float* __restrict__ inb,
                                                const float* __restrict__ edgeW,
                                                const float* __restrict__ attSg,
                                                const float* __restrict__ attDg,
                                                const float* __restrict__ attEg,
                                                const float* __restrict__ gbias,
                                                const float* __restrict__ glns,
                                                const float* __restrict__ glnb,
                                                float* __restrict__ framebuf) {
    int bt = blockIdx.x;
    size_t fbase = (size_t)bt * 64 * 256;

    __shared__ unsigned short U[256 * 136];      // 69632 B: x planes OR hT (aliased)
    __shared__ float pxS[64], pyS[64], vmS[64];
    __shared__ float loopS[192];
    __shared__ float asrcS[8][64], adstS[8][64]; // per-WAVE partials (2 waves per head)
    __shared__ float wESall[36];                 // [l][e][h]
    __shared__ float sumsS[64][8];
    __shared__ float mrsS[64][2];
    __shared__ float nvS;

    int tid = threadIdx.x, lane = tid & 63, w = tid >> 6;
    int ln15 = lane & 15, q = lane >> 4;
    int nt0 = w * 2;
    int head = w >> 1;
    int base_d = (w & 1) * 32;

    unsigned short* xH = U;                  // x hi plane  [64][XP]
    unsigned short* xL = U + 64 * XP;        // x lo plane  [64][XP]
    // hT view: U[c*136 + s], s 0..63 = hi, 64..127 = lo

    // ---- Phase 0a: geometry + per-layer wES + feats staging (pre-split) ----
    if (tid < 64) {
        const float* bx = boxes + (size_t)(bt * 64 + tid) * 5;
        pxS[tid] = bx[1];
        pyS[tid] = bx[2];
        vmS[tid] = maskp[bt * 64 + tid];
    } else if (tid < 100) {
        int idx = tid - 64;                  // l*12 + e*4 + h2
        int l = idx / 12, r2 = idx - l * 12;
        int e = r2 >> 2, h2 = r2 & 3;
        float sm = 0.f;
        const float* ew = edgeW + (size_t)l * 768 + e * 256 + h2 * 64;
        const float* ae = attEg + (size_t)l * 256 + h2 * 64;
        for (int c = 0; c < 64; c++) sm += ew[c] * ae[c];
        wESall[idx] = sm;
    }
    #pragma unroll
    for (int j = 0; j < 8; j++) {
        int g = j * 2048 + tid * 4;
        int row = g >> 8, col = g & 255;
        float4 v4 = *(const float4*)&feats[fbase + g];
        union { u16x4 v; unsigned short u[4]; } H4, L4;
        float vf[4] = {v4.x, v4.y, v4.z, v4.w};
        #pragma unroll
        for (int jj = 0; jj < 4; jj++) {
            H4.u[jj] = f2bf(vf[jj]);
            L4.u[jj] = f2bf(vf[jj] - bf2f(H4.u[jj]));
        }
        *(u16x4*)&xH[row * XP + col] = H4.v;
        *(u16x4*)&xL[row * XP + col] = L4.v;
    }
    __syncthreads();

    // ---- Phase 0b: self-loop edge-attr averages + nvalid ----
    {
        int d = tid >> 3, part = tid & 7;
        float pxd = pxS[d], pyd = pyS[d];
        bool vd = vmS[d] > 0.5f;
        float deg = 0.f, s0 = 0.f, s1 = 0.f, s2 = 0.f;
        #pragma unroll
        for (int k = 0; k < 8; k++) {
            int s = part * 8 + k;
            float rx = pxd - pxS[s], ry = pyd - pyS[s];
            float dist = sqrtf(fmaxf(rx * rx + ry * ry, 1e-12f));
            bool adj = vd && (vmS[s] > 0.5f) && (dist < 0.3f) && (s != d);
            if (adj) { deg += 1.f; s0 += dist; s1 += rx; s2 += ry; }
        }
        #pragma unroll
        for (int off = 1; off < 8; off <<= 1) {
            deg += __shfl_xor(deg, off);
            s0  += __shfl_xor(s0, off);
            s1  += __shfl_xor(s1, off);
            s2  += __shfl_xor(s2, off);
        }
        if (part == 0) {
            float dg = fmaxf(deg, 1.f);
            loopS[d * 3 + 0] = s0 / dg;
            loopS[d * 3 + 1] = s1 / dg;
            loopS[d * 3 + 2] = s2 / dg;
        }
    }
    if (tid == 0) {
        float nv = 0.f;
        for (int m = 0; m < 64; m++) nv += vmS[m] > 0.5f ? 1.f : 0.f;
        nvS = fmaxf(nv, 1.f);
    }

    // ---- Phase 0c: in_proj MFMA (A = staged feats in U, B = Bsw mat 0) ----
    {
        f32x4 acc[4][2];
        #pragma unroll
        for (int mt = 0; mt < 4; mt++)
            #pragma unroll
            for (int ntl = 0; ntl < 2; ntl++) acc[mt][ntl] = (f32x4){0.f, 0.f, 0.f, 0.f};
        for (int ks = 0; ks < 8; ks++) {
            bf16x8 bhi[2], blo[2];
            #pragma unroll
            for (int ntl = 0; ntl < 2; ntl++) {
                const unsigned short* fb = &BswAll[((size_t)(ks * 16 + nt0 + ntl) * 64 + lane) * 16];
                bhi[ntl] = *(const bf16x8*)&fb[0];
                blo[ntl] = *(const bf16x8*)&fb[8];
            }
            #pragma unroll
            for (int mt = 0; mt < 4; mt++) {
                int ao = (mt * 16 + ln15) * XP + ks * 32 + q * 8;
                bf16x8 ahi = *(const bf16x8*)&xH[ao];
                bf16x8 alo = *(const bf16x8*)&xL[ao];
                #pragma unroll
                for (int ntl = 0; ntl < 2; ntl++) {
                    acc[mt][ntl] = __builtin_amdgcn_mfma_f32_16x16x32_bf16(ahi, bhi[ntl], acc[mt][ntl], 0, 0, 0);
                    acc[mt][ntl] = __builtin_amdgcn_mfma_f32_16x16x32_bf16(alo, bhi[ntl], acc[mt][ntl], 0, 0, 0);
                    acc[mt][ntl] = __builtin_amdgcn_mfma_f32_16x16x32_bf16(ahi, blo[ntl], acc[mt][ntl], 0, 0, 0);
                }
            }
        }
        __syncthreads();   // all feats reads from U done; safe to overwrite with x
        #pragma unroll
        for (int ntl = 0; ntl < 2; ntl++) {
            int c = (nt0 + ntl) * 16 + ln15;
            float bv = inb[c];
            #pragma unroll
            for (int mt = 0; mt < 4; mt++) {
                #pragma unroll
                for (int r = 0; r < 4; r++) {
                    int m = mt * 16 + q * 4 + r;
                    float v = (acc[mt][ntl][r] + bv) * (vmS[m] > 0.5f ? 1.f : 0.f);
                    unsigned short hi = f2bf(v);
                    xH[m * XP + c] = hi;
                    xL[m * XP + c] = f2bf(v - bf2f(hi));
                }
            }
        }
    }
    __syncthreads();

    // ---- 3 GAT layers, x resident in LDS (union with hT) ----
    for (int l = 0; l < 3; l++) {
        const unsigned short* BswL = BswAll + (size_t)(1 + l) * 16384 * 16;
        const float* attSl = attSg + (size_t)l * 256;
        const float* attDl = attDg + (size_t)l * 256;
        const float* biasl = gbias + (size_t)l * 256;
        const float* lnsl  = glns + (size_t)l * 256;
        const float* lnbl  = glnb + (size_t)l * 256;
        const float* wES   = wESall + l * 12;

        // Phase B: h = x @ W (both operands pre-split in LDS/global)
        f32x4 acc[4][2];
        #pragma unroll
        for (int mt = 0; mt < 4; mt++)
            #pragma unroll
            for (int ntl = 0; ntl < 2; ntl++) acc[mt][ntl] = (f32x4){0.f, 0.f, 0.f, 0.f};
        for (int ks = 0; ks < 8; ks++) {
            bf16x8 bhi[2], blo[2];
            #pragma unroll
            for (int ntl = 0; ntl < 2; ntl++) {
                const unsigned short* fb = &BswL[((size_t)(ks * 16 + nt0 + ntl) * 64 + lane) * 16];
                bhi[ntl] = *(const bf16x8*)&fb[0];
                blo[ntl] = *(const bf16x8*)&fb[8];
            }
            #pragma unroll
            for (int mt = 0; mt < 4; mt++) {
                int ao = (mt * 16 + ln15) * XP + ks * 32 + q * 8;
                bf16x8 ahi = *(const bf16x8*)&xH[ao];
                bf16x8 alo = *(const bf16x8*)&xL[ao];
                #pragma unroll
                for (int ntl = 0; ntl < 2; ntl++) {
                    acc[mt][ntl] = __builtin_amdgcn_mfma_f32_16x16x32_bf16(ahi, bhi[ntl], acc[mt][ntl], 0, 0, 0);
                    acc[mt][ntl] = __builtin_amdgcn_mfma_f32_16x16x32_bf16(alo, bhi[ntl], acc[mt][ntl], 0, 0, 0);
                    acc[mt][ntl] = __builtin_amdgcn_mfma_f32_16x16x32_bf16(ahi, blo[ntl], acc[mt][ntl], 0, 0, 0);
                }
            }
        }

        // macc init: fold residual x_old + bias into the P.H MFMA C-operand.
        // Read from U (x layout) BEFORE phase C overwrites it with hT.
        f32x4 macc[2][4];
        {
            #pragma unroll
            for (int ct = 0; ct < 4; ct++) {
                int c = head * 64 + ct * 16 + ln15;
                float bv = biasl[c];
                #pragma unroll
                for (int t = 0; t < 2; t++) {
                    #pragma unroll
                    for (int r = 0; r < 4; r++) {
                        int d = base_d + t * 16 + q * 4 + r;
                        int o = d * XP + c;
                        macc[t][ct][r] = bf2f(xH[o]) + bf2f(xL[o]) + bv;
                    }
                }
            }
        }
        __syncthreads();   // all x reads done; U may be overwritten with hT

        // Phase C: h -> hT (into U) + per-wave a_src/a_dst partials.
        {
            float pSrc[4][4], pDst[4][4];
            #pragma unroll
            for (int mt = 0; mt < 4; mt++)
                #pragma unroll
                for (int r = 0; r < 4; r++) { pSrc[mt][r] = 0.f; pDst[mt][r] = 0.f; }
            #pragma unroll
            for (int ntl = 0; ntl < 2; ntl++) {
                int c = (nt0 + ntl) * 16 + ln15;
                float aS = attSl[c], aD = attDl[c];
                #pragma unroll
                for (int mt = 0; mt < 4; mt++) {
                    #pragma unroll
                    for (int r = 0; r < 4; r++) {
                        float v = acc[mt][ntl][r];
                        pSrc[mt][r] = fmaf(v, aS, pSrc[mt][r]);
                        pDst[mt][r] = fmaf(v, aD, pDst[mt][r]);
                        unsigned short hi = f2bf(v);
                        unsigned short lo = f2bf(v - bf2f(hi));
                        int s = mt * 16 + q * 4 + r;
                        U[c * 136 + s] = hi;
                        U[c * 136 + 64 + s] = lo;
                    }
                }
            }
            #pragma unroll
            for (int off = 1; off < 16; off <<= 1) {
                #pragma unroll
                for (int mt = 0; mt < 4; mt++)
                    #pragma unroll
                    for (int r = 0; r < 4; r++) {
                        pSrc[mt][r] += __shfl_xor(pSrc[mt][r], off);
                        pDst[mt][r] += __shfl_xor(pDst[mt][r], off);
                    }
            }
            if (ln15 == 0) {
                #pragma unroll
                for (int mt = 0; mt < 4; mt++)
                    #pragma unroll
                    for (int r = 0; r < 4; r++) {
                        int m = mt * 16 + q * 4 + r;
                        asrcS[w][m] = pSrc[mt][r];
                        adstS[w][m] = pDst[mt][r];
                    }
            }
        }
        __syncthreads();

        // Phase E: per d-tile (sequential to cap VGPR): logits -> softmax ->
        // alpha hi/lo A-frags -> P.H MFMA accumulating into macc.
        {
            float we0 = wES[head], we1 = wES[4 + head], we2 = wES[8 + head];
            #pragma unroll
            for (int t = 0; t < 2; t++) {
                int d = base_d + t * 16 + ln15;
                float pxd = pxS[d], pyd = pyS[d];
                bool vdv = vmS[d] > 0.5f;
                float adstv = adstS[2 * head][d] + adstS[2 * head + 1][d];
                float lp0 = loopS[d * 3 + 0];
                float lp1 = loopS[d * 3 + 1];
                float lp2 = loopS[d * 3 + 2];

                float lg[16];
                #pragma unroll
                for (int ks = 0; ks < 2; ks++) {
                    int s0 = ks * 32 + q * 8;
                    F8 PX, PY, VM, AS, A1;
                    PX.v2[0] = *(const float4*)&pxS[s0]; PX.v2[1] = *(const float4*)&pxS[s0 + 4];
                    PY.v2[0] = *(const float4*)&pyS[s0]; PY.v2[1] = *(const float4*)&pyS[s0 + 4];
                    VM.v2[0] = *(const float4*)&vmS[s0]; VM.v2[1] = *(const float4*)&vmS[s0 + 4];
                    AS.v2[0] = *(const float4*)&asrcS[2 * head][s0];
                    AS.v2[1] = *(const float4*)&asrcS[2 * head][s0 + 4];
                    A1.v2[0] = *(const float4*)&asrcS[2 * head + 1][s0];
                    A1.v2[1] = *(const float4*)&asrcS[2 * head + 1][s0 + 4];
                    #pragma unroll
                    for (int j = 0; j < 8; j++) {
                        int s = s0 + j;
                        float vsf = VM.f[j];
                        float asv = AS.f[j] + A1.f[j];
                        float rx = pxd - PX.f[j], ry = pyd - PY.f[j];
                        float dist = sqrtf(fmaxf(rx * rx + ry * ry, 1e-12f));
                        bool self = (s == d);
                        bool adj = vdv && (vsf > 0.5f) && (dist < 0.3f) && !self;
                        float e0 = adj ? dist : (self ? lp0 : 0.f);
                        float e1 = adj ? rx   : (self ? lp1 : 0.f);
                        float e2 = adj ? ry   : (self ? lp2 : 0.f);
                        bool fa = adj || (self && vdv);
                        float lv = asv + adstv + e0 * we0 + e1 * we1 + e2 * we2;
                        lv = lv >= 0.f ? lv : 0.2f * lv;
                        lg[ks * 8 + j] = fa ? lv : -1e9f;
                    }
                }

                // softmax over s (in-lane 16 + xor16/xor32 over q)
                float mx = lg[0];
                #pragma unroll
                for (int j = 1; j < 16; j++) mx = fmaxf(mx, lg[j]);
                mx = fmaxf(mx, __shfl_xor(mx, 16));
                mx = fmaxf(mx, __shfl_xor(mx, 32));
                float sm = 0.f;
                #pragma unroll
                for (int j = 0; j < 16; j++) { lg[j] = __expf(lg[j] - mx); sm += lg[j]; }
                sm += __shfl_xor(sm, 16);
                sm += __shfl_xor(sm, 32);
                float inv = 1.f / sm;

                bf16x8 ah[2], al[2];
                #pragma unroll
                for (int ks2 = 0; ks2 < 2; ks2++) {
                    union { bf16x8 v; unsigned short u[8]; } H, L;
                    #pragma unroll
                    for (int j = 0; j < 8; j++) {
                        float a = lg[ks2 * 8 + j] * inv;
                        unsigned short hi = f2bf(a);
                        H.u[j] = hi;
                        L.u[j] = f2bf(a - bf2f(hi));
                    }
                    ah[ks2] = H.v; al[ks2] = L.v;
                }

                // P.H MFMA: msg[d][c] for this d-tile, c in head*64..+64
                #pragma unroll
                for (int ks2 = 0; ks2 < 2; ks2++) {
                    #pragma unroll
                    for (int ct = 0; ct < 4; ct++) {
                        const unsigned short* hb =
                            &U[(size_t)(head * 64 + ct * 16 + ln15) * 136 + ks2 * 32 + q * 8];
                        bf16x8 bhi = *(const bf16x8*)&hb[0];
                        bf16x8 blo = *(const bf16x8*)&hb[64];
                        macc[t][ct] = __builtin_amdgcn_mfma_f32_16x16x32_bf16(ah[ks2], bhi, macc[t][ct], 0, 0, 0);
                        macc[t][ct] = __builtin_amdgcn_mfma_f32_16x16x32_bf16(al[ks2], bhi, macc[t][ct], 0, 0, 0);
                        macc[t][ct] = __builtin_amdgcn_mfma_f32_16x16x32_bf16(ah[ks2], blo, macc[t][ct], 0, 0, 0);
                    }
                }
            }
        }

        // Phase F: LN + relu (macc already = msg + x_old + bias), write new x.
        {
            float scv[4], bbv[4];
            #pragma unroll
            for (int ct = 0; ct < 4; ct++) {
                int c = head * 64 + ct * 16 + ln15;
                scv[ct] = lnsl[c];
                bbv[ct] = lnbl[c];
            }
            float ps[8], ps2[8];
            #pragma unroll
            for (int t = 0; t < 2; t++)
                #pragma unroll
                for (int r = 0; r < 4; r++) {
                    float s = 0.f, s2 = 0.f;
                    #pragma unroll
                    for (int ct = 0; ct < 4; ct++) {
                        float v = macc[t][ct][r];
                        s += v; s2 += v * v;
                    }
                    ps[t * 4 + r] = s; ps2[t * 4 + r] = s2;
                }
            #pragma unroll
            for (int off = 1; off < 16; off <<= 1) {
                #pragma unroll
                for (int i = 0; i < 8; i++) {
                    ps[i]  += __shfl_xor(ps[i], off);
                    ps2[i] += __shfl_xor(ps2[i], off);
                }
            }
            if (ln15 == 0) {
                #pragma unroll
                for (int t = 0; t < 2; t++)
                    #pragma unroll
                    for (int r = 0; r < 4; r++) {
                        int d = base_d + t * 16 + q * 4 + r;
                        sumsS[d][head * 2 + 0] = ps[t * 4 + r];
                        sumsS[d][head * 2 + 1] = ps2[t * 4 + r];
                    }
            }
            __syncthreads();   // also guarantees: all waves finished hT reads
            if (tid < 64) {
                float S  = sumsS[tid][0] + sumsS[tid][2] + sumsS[tid][4] + sumsS[tid][6];
                float S2 = sumsS[tid][1] + sumsS[tid][3] + sumsS[tid][5] + sumsS[tid][7];
                float mu = S * (1.f / 256.f);
                float var = S2 * (1.f / 256.f) - mu * mu;
                mrsS[tid][0] = mu;
                mrsS[tid][1] = rsqrtf(var + 1e-5f);
            }
            __syncthreads();
            #pragma unroll
            for (int t = 0; t < 2; t++)
                #pragma unroll
                for (int r = 0; r < 4; r++) {
                    int d = base_d + t * 16 + q * 4 + r;
                    float mu = mrsS[d][0], rs = mrsS[d][1];
                    #pragma unroll
                    for (int ct = 0; ct < 4; ct++) {
                        float v = (macc[t][ct][r] - mu) * rs * scv[ct] + bbv[ct];
                        v = fmaxf(v, 0.f);
                        unsigned short hi = f2bf(v);
                        int o = d * XP + head * 64 + ct * 16 + ln15;
                        xH[o] = hi;
                        xL[o] = f2bf(v - bf2f(hi));
                    }
                }
        }
        __syncthreads();   // x ready for next layer / frame mean
    }

    // ---- masked frame mean -> framebuf ----
    if (tid < 256) {
        float s = 0.f;
        for (int m = 0; m < 64; m++) {
            float xv = bf2f(xH[m * XP + tid]) + bf2f(xL[m * XP + tid]);
            s += xv * (vmS[m] > 0.5f ? 1.f : 0.f);
        }
        framebuf[(size_t)bt * 256 + tid] = s / nvS;
    }
}

// ---------------------------------------------------------------------------
// temp proj from precomputed frame means, 4 tokens per block
__global__ __launch_bounds__(256) void k_temp4(const float* __restrict__ framebuf,
                                               const float* __restrict__ tW,
                                               const float* __restrict__ tb,
                                               const float* __restrict__ pe,
                                               float* __restrict__ ybuf) {
    int b4 = blockIdx.x;   // 0..511
    int tid = threadIdx.x;
    __shared__ float frS[4][256];
    #pragma unroll
    for (int t = 0; t < 4; t++) frS[t][tid] = framebuf[(size_t)(b4 * 4 + t) * 256 + tid];
    __syncthreads();
    float acc[4];
    #pragma unroll
    for (int t = 0; t < 4; t++) acc[t] = tb[tid] + pe[((b4 * 4 + t) & 31) * 256 + tid];
    const float* wrow = tW + (size_t)tid * 256;
    for (int g = 0; g < 256; g += 4) {
        float4 wv = *(const float4*)&wrow[g];
        #pragma unroll
        for (int t = 0; t < 4; t++) acc[t] += dot4(*(const float4*)&frS[t][g], wv);
    }
    #pragma unroll
    for (int t = 0; t < 4; t++) ybuf[(size_t)(b4 * 4 + t) * 256 + tid] = acc[t];
}

// ---------------------------------------------------------------------------
// LN1 + qkv, 4 tokens per block; wave-per-token LN.
__global__ __launch_bounds__(256) void k_ln_qkv4(const float* __restrict__ ybuf,
                                                 const float* __restrict__ ln_s,
                                                 const float* __restrict__ ln_b,
                                                 const float* __restrict__ qW,
                                                 const float* __restrict__ qb,
                                                 float* __restrict__ qkvbuf) {
    int b4 = blockIdx.x, tid = threadIdx.x;
    int lane = tid & 63, wv = tid >> 6;
    __shared__ float zS[4][256];
    {
        int bt = b4 * 4 + wv;
        float4 yv = *(const float4*)&ybuf[(size_t)bt * 256 + lane * 4];
        float s = yv.x + yv.y + yv.z + yv.w;
        float s2 = yv.x * yv.x + yv.y * yv.y + yv.z * yv.z + yv.w * yv.w;
        #pragma unroll
        for (int off = 1; off < 64; off <<= 1) { s += __shfl_xor(s, off); s2 += __shfl_xor(s2, off); }
        float mu = s * (1.f / 256.f);
        float var = s2 * (1.f / 256.f) - mu * mu;
        float rstd = rsqrtf(var + 1e-5f);
        float4 ls = *(const float4*)&ln_s[lane * 4];
        float4 lb = *(const float4*)&ln_b[lane * 4];
        float4 z;
        z.x = (yv.x - mu) * rstd * ls.x + lb.x;
        z.y = (yv.y - mu) * rstd * ls.y + lb.y;
        z.z = (yv.z - mu) * rstd * ls.z + lb.z;
        z.w = (yv.w - mu) * rstd * ls.w + lb.w;
        *(float4*)&zS[wv][lane * 4] = z;
    }
    __syncthreads();
    for (int r = 0; r < 3; r++) {
        int j = r * 256 + tid;
        float acc[4];
        float bv = qb[j];
        #pragma unroll
        for (int t = 0; t < 4; t++) acc[t] = bv;
        const float* wrow = qW + (size_t)j * 256;
        for (int i = 0; i < 256; i += 4) {
            float4 wv4 = *(const float4*)&wrow[i];
            #pragma unroll
            for (int t = 0; t < 4; t++) acc[t] += dot4(*(const float4*)&zS[t][i], wv4);
        }
        #pragma unroll
        for (int t = 0; t < 4; t++) qkvbuf[(size_t)(b4 * 4 + t) * 768 + j] = acc[t];
    }
}

// ---------------------------------------------------------------------------
__global__ __launch_bounds__(64) void k_attn(const float* __restrict__ qkvbuf,
                                             float* __restrict__ obuf) {
    int blk = blockIdx.x;
    int b = blk >> 3, h = blk & 7;
    int tid = threadIdx.x;
    __shared__ float Ks[32 * 32], Vs[32 * 32];
    for (int idx = tid; idx < 1024; idx += 64) {
        int tk = idx >> 5, c = idx & 31;
        size_t qbase = ((size_t)(b * 32 + tk)) * 768 + h * 32 + c;
        Ks[idx] = qkvbuf[qbase + 256];
        Vs[idx] = qkvbuf[qbase + 512];
    }
    __syncthreads();
    if (tid < 32) {
        int tq = tid;
        float qv[32];
        size_t qb0 = ((size_t)(b * 32 + tq)) * 768 + h * 32;
        #pragma unroll
        for (int c = 0; c < 32; c++) qv[c] = qkvbuf[qb0 + c];
        float scr[32];
        float mx = -1e30f;
        #pragma unroll
        for (int tk = 0; tk < 32; tk++) {
            float dd = 0.f;
            #pragma unroll
            for (int c = 0; c < 32; c++) dd = fmaf(qv[c], Ks[tk * 32 + c], dd);
            dd *= 0.17677669529663687f;
            scr[tk] = dd;
            mx = fmaxf(mx, dd);
        }
        float sm = 0.f;
        #pragma unroll
        for (int tk = 0; tk < 32; tk++) { scr[tk] = __expf(scr[tk] - mx); sm += scr[tk]; }
        float inv = 1.f / sm;
        float o[32];
        #pragma unroll
        for (int c = 0; c < 32; c++) o[c] = 0.f;
        #pragma unroll
        for (int tk = 0; tk < 32; tk++) {
            float a = scr[tk] * inv;
            #pragma unroll
            for (int c = 0; c < 32; c++) o[c] = fmaf(a, Vs[tk * 32 + c], o[c]);
        }
        size_t ob = ((size_t)(b * 32 + tq)) * 256 + h * 32;
        #pragma unroll
        for (int c = 0; c < 32; c++) obuf[ob + c] = o[c];
    }
}

// ---------------------------------------------------------------------------
__global__ __launch_bounds__(256) void k_attn_out4(const float* __restrict__ obuf,
                                                   const float* __restrict__ W,
                                                   const float* __restrict__ bvec,
                                                   float* __restrict__ ybuf) {
    int b4 = blockIdx.x, tid = threadIdx.x;
    int lane = tid & 63, wv = tid >> 6;
    __shared__ float oS[4][256];
    *(float4*)&oS[wv][lane * 4] = *(const float4*)&obuf[(size_t)(b4 * 4 + wv) * 256 + lane * 4];
    __syncthreads();
    float acc[4];
    float bv = bvec[tid];
    #pragma unroll
    for (int t = 0; t < 4; t++) acc[t] = bv;
    const float* wrow = W + (size_t)tid * 256;
    for (int i = 0; i < 256; i += 4) {
        float4 wv4 = *(const float4*)&wrow[i];
        #pragma unroll
        for (int t = 0; t < 4; t++) acc[t] += dot4(*(const float4*)&oS[t][i], wv4);
    }
    #pragma unroll
    for (int t = 0; t < 4; t++) ybuf[(size_t)(b4 * 4 + t) * 256 + tid] += acc[t];
}

// ---------------------------------------------------------------------------
__global__ __launch_bounds__(256) void k_ff4(float* __restrict__ ybuf,
                                             const float* __restrict__ ln_s,
                                             const float* __restrict__ ln_b,
                                             const float* __restrict__ W1,
                                             const float* __restrict__ b1,
                                             const float* __restrict__ W2,
                                             const float* __restrict__ b2) {
    int b4 = blockIdx.x, tid = threadIdx.x;
    int lane = tid & 63, wv = tid >> 6;
    __shared__ float zS[4][256];
    __shared__ float fS[4][512];
    {
        int bt = b4 * 4 + wv;
        float4 yv = *(const float4*)&ybuf[(size_t)bt * 256 + lane * 4];
        float s = yv.x + yv.y + yv.z + yv.w;
        float s2 = yv.x * yv.x + yv.y * yv.y + yv.z * yv.z + yv.w * yv.w;
        #pragma unroll
        for (int off = 1; off < 64; off <<= 1) { s += __shfl_xor(s, off); s2 += __shfl_xor(s2, off); }
        float mu = s * (1.f / 256.f);
        float var = s2 * (1.f / 256.f) - mu * mu;
        float rstd = rsqrtf(var + 1e-5f);
        float4 ls = *(const float4*)&ln_s[lane * 4];
        float4 lb = *(const float4*)&ln_b[lane * 4];
        float4 z;
        z.x = (yv.x - mu) * rstd * ls.x + lb.x;
        z.y = (yv.y - mu) * rstd * ls.y + lb.y;
        z.z = (yv.z - mu) * rstd * ls.z + lb.z;
        z.w = (yv.w - mu) * rstd * ls.w + lb.w;
        *(float4*)&zS[wv][lane * 4] = z;
    }
    __syncthreads();
    for (int r = 0; r < 2; r++) {
        int j = r * 256 + tid;
        float acc[4];
        float bv = b1[j];
        #pragma unroll
        for (int t = 0; t < 4; t++) acc[t] = bv;
        const float* wrow = W1 + (size_t)j * 256;
        for (int i = 0; i < 256; i += 4) {
            float4 wv4 = *(const float4*)&wrow[i];
            #pragma unroll
            for (int t = 0; t < 4; t++) acc[t] += dot4(*(const float4*)&zS[t][i], wv4);
        }
        #pragma unroll
        for (int t = 0; t < 4; t++) fS[t][j] = fmaxf(acc[t], 0.f);
    }
    __syncthreads();
    float acc[4];
    float bv = b2[tid];
    #pragma unroll
    for (int t = 0; t < 4; t++) acc[t] = bv;
    const float* wrow = W2 + (size_t)tid * 512;
    for (int jj = 0; jj < 512; jj += 4) {
        float4 wv4 = *(const float4*)&wrow[jj];
        #pragma unroll
        for (int t = 0; t < 4; t++) acc[t] += dot4(*(const float4*)&fS[t][jj], wv4);
    }
    #pragma unroll
    for (int t = 0; t < 4; t++) {
        size_t idx = (size_t)(b4 * 4 + t) * 256 + tid;
        ybuf[idx] = ybuf[idx] + acc[t];
    }
}

// ---------------------------------------------------------------------------
__global__ __launch_bounds__(256) void k_pool_out(const float* __restrict__ ybuf,
                                                  const float* __restrict__ pW,
                                                  const float* __restrict__ pb,
                                                  const float* __restrict__ oW,
                                                  const float* __restrict__ ob,
                                                  const float* __restrict__ lns,
                                                  const float* __restrict__ lnb,
                                                  float* __restrict__ dout) {
    int b = blockIdx.x, tid = threadIdx.x;
    __shared__ float redP[256];
    __shared__ float wS[32];
    __shared__ float pS[256];
    __shared__ float red[8];
    int tq = tid >> 3, part = tid & 7;
    float partial = 0.f;
    {
        const float* yrow = ybuf + ((size_t)(b * 32 + tq)) * 256 + part * 32;
        const float* pwp = pW + part * 32;
        #pragma unroll
        for (int j = 0; j < 32; j += 4) {
            float4 yv = *(const float4*)&yrow[j];
            float4 wv = *(const float4*)&pwp[j];
            partial += dot4(yv, wv);
        }
    }
    redP[tid] = partial;
    __syncthreads();
    if (tid < 32) {
        float s = pb[0];
        for (int p = 0; p < 8; p++) s += redP[tid * 8 + p];
        float mx = s;
        #pragma unroll
        for (int off = 16; off; off >>= 1) mx = fmaxf(mx, __shfl_xor(mx, off));
        float e = __expf(s - mx);
        float sm = e;
        #pragma unroll
        for (int off = 16; off; off >>= 1) sm += __shfl_xor(sm, off);
        wS[tid] = e / sm;
    }
    __syncthreads();
    float p = 0.f;
    for (int t = 0; t < 32; t++) p += ybuf[((size_t)(b * 32 + t)) * 256 + tid] * wS[t];
    pS[tid] = p;
    __syncthreads();
    float accs[2];
    for (int r = 0; r < 2; r++) {
        int j = r * 256 + tid;
        float acc = ob[j];
        const float* wrow = oW + (size_t)j * 256;
        for (int g = 0; g < 256; g += 4) {
            float4 pv = *(const float4*)&pS[g];
            float4 wv = *(const float4*)&wrow[g];
            acc += dot4(pv, wv);
        }
        accs[r] = acc;
    }
    float s = accs[0] + accs[1];
    float s2 = accs[0] * accs[0] + accs[1] * accs[1];
    #pragma unroll
    for (int off = 32; off; off >>= 1) {
        s += __shfl_xor(s, off);
        s2 += __shfl_xor(s2, off);
    }
    int wid = threadIdx.x >> 6;
    int lane = threadIdx.x & 63;
    if (lane == 0) { red[wid] = s; red[4 + wid] = s2; }
    __syncthreads();
    s = red[0] + red[1] + red[2] + red[3];
    s2 = red[4] + red[5] + red[6] + red[7];
    float mu = s * (1.f / 512.f);
    float var = s2 * (1.f / 512.f) - mu * mu;
    float rstd = rsqrtf(var + 1e-5f);
    dout[b * 512 + tid]       = fmaxf((accs[0] - mu) * rstd * lns[tid] + lnb[tid], 0.f);
    dout[b * 512 + tid + 256] = fmaxf((accs[1] - mu) * rstd * lns[tid + 256] + lnb[tid + 256], 0.f);
}

// ---------------------------------------------------------------------------
extern "C" void kernel_launch(void* const* d_in, const int* in_sizes, int n_in,
                              void* d_out, int out_size, void* d_ws, size_t ws_size,
                              hipStream_t stream) {
    const float* drone_feats = (const float*)d_in[0];
    const float* boxes       = (const float*)d_in[1];
    const float* drone_mask  = (const float*)d_in[2];
    const float* in_proj_W   = (const float*)d_in[3];
    const float* in_proj_b   = (const float*)d_in[4];
    const float* gat_lin_W   = (const float*)d_in[5];
    const float* gat_edge_W  = (const float*)d_in[6];
    const float* gat_att_src = (const float*)d_in[7];
    const float* gat_att_dst = (const float*)d_in[8];
    const float* gat_att_edge= (const float*)d_in[9];
    const float* gat_bias    = (const float*)d_in[10];
    const float* gat_ln_s    = (const float*)d_in[11];
    const float* gat_ln_b    = (const float*)d_in[12];
    const float* temp_W      = (const float*)d_in[13];
    const float* temp_b      = (const float*)d_in[14];
    const float* pos_emb     = (const float*)d_in[15];
    const float* qkv_W       = (const float*)d_in[16];
    const float* qkv_b       = (const float*)d_in[17];
    const float* attn_out_W  = (const float*)d_in[18];
    const float* attn_out_b  = (const float*)d_in[19];
    const float* ln1_s       = (const float*)d_in[20];
    const float* ln1_b       = (const float*)d_in[21];
    const float* ln2_s       = (const float*)d_in[22];
    const float* ln2_b       = (const float*)d_in[23];
    const float* ff1_W       = (const float*)d_in[24];
    const float* ff1_b       = (const float*)d_in[25];
    const float* ff2_W       = (const float*)d_in[26];
    const float* ff2_b       = (const float*)d_in[27];
    const float* pool_W      = (const float*)d_in[28];
    const float* pool_b      = (const float*)d_in[29];
    const float* out_W       = (const float*)d_in[30];
    const float* out_b       = (const float*)d_in[31];
    const float* out_ln_s    = (const float*)d_in[32];
    const float* out_ln_b    = (const float*)d_in[33];
    float* out = (float*)d_out;

    float* ws = (float*)d_ws;
    unsigned short* Bsw = (unsigned short*)ws;           // 4*16384*16 ushorts = 2 MB
    size_t off = (size_t)(4 * 16384 * 16) / 2;           // in floats
    float* framebuf = ws + off; off += (size_t)BT * 256;
    float* ybuf   = ws + off; off += (size_t)BT * 256;
    float* qkvbuf = ws + off; off += (size_t)BT * 768;
    float* obuf   = ws + off; off += (size_t)BT * 256;

    k_prep<<<dim3(256), dim3(256), 0, stream>>>(in_proj_W, gat_lin_W, Bsw);
    k_gnn<<<dim3(BT), dim3(512), 0, stream>>>(drone_feats, boxes, drone_mask, Bsw,
        in_proj_b, gat_edge_W, gat_att_src, gat_att_dst, gat_att_edge,
        gat_bias, gat_ln_s, gat_ln_b, framebuf);
    k_temp4<<<dim3(BT / 4), dim3(256), 0, stream>>>(framebuf, temp_W, temp_b, pos_emb, ybuf);
    for (int l = 0; l < 2; l++) {
        k_ln_qkv4<<<dim3(BT / 4), dim3(256), 0, stream>>>(ybuf, ln1_s + l * 256, ln1_b + l * 256,
            qkv_W + (size_t)l * 768 * 256, qkv_b + l * 768, qkvbuf);
        k_attn<<<dim3(512), dim3(64), 0, stream>>>(qkvbuf, obuf);
        k_attn_out4<<<dim3(BT / 4), dim3(256), 0, stream>>>(obuf,
            attn_out_W + (size_t)l * 65536, attn_out_b + l * 256, ybuf);
        k_ff4<<<dim3(BT / 4), dim3(256), 0, stream>>>(ybuf, ln2_s + l * 256, ln2_b + l * 256,
            ff1_W + (size_t)l * 131072, ff1_b + l * 512,
            ff2_W + (size_t)l * 131072, ff2_b + l * 256);
    }
    k_pool_out<<<dim3(64), dim3(256), 0, stream>>>(ybuf, pool_W, pool_b, out_W, out_b,
                                                   out_ln_s, out_ln_b, out);
}

// Round 4
// 1133.326 us; speedup vs baseline: 1.0659x; 1.0659x over previous
//
#include <hip/hip_runtime.h>
#include <math.h>

#define BT 2048

typedef __attribute__((ext_vector_type(8))) short bf16x8;
typedef __attribute__((ext_vector_type(4))) float f32x4;
typedef __attribute__((ext_vector_type(4))) unsigned short u16x4;

__device__ inline unsigned short f2bf(float f) {
    union { float f; unsigned u; } v; v.f = f;
    unsigned r = (v.u >> 16) & 1u;
    return (unsigned short)((v.u + 0x7FFFu + r) >> 16);
}
__device__ inline float bf2f(unsigned short s) {
    union { unsigned u; float f; } v; v.u = ((unsigned)s) << 16;
    return v.f;
}

__device__ inline float dot4(const float4 a, const float4 b) {
    return fmaf(a.x, b.x, fmaf(a.y, b.y, fmaf(a.z, b.z, a.w * b.w)));
}

union F8 { float4 v2[2]; float f[8]; };

// x/feats LDS planes: [64 rows][264 cols] ushort (pad 8 cols kills stride-256 conflicts)
#define XP 264

// ---------------------------------------------------------------------------
// Pre-swizzle weights into MFMA B-fragment order, SPLIT bf16 hi/lo.
__global__ __launch_bounds__(256) void k_prep(const float* __restrict__ inW,
                                              const float* __restrict__ gatW,
                                              unsigned short* __restrict__ dst) {
    int gid = blockIdx.x * 256 + threadIdx.x;   // 0..65535
    int mat = gid >> 14;
    int r   = gid & 16383;
    int ks  = r >> 10;
    int nt  = (r >> 6) & 15;
    int lane = r & 63;
    int ln15 = lane & 15, q = lane >> 4;
    int n  = nt * 16 + ln15;
    int k0 = ks * 32 + q * 8;
    const float* src; bool tr;
    if (mat == 0) { src = inW; tr = true; }
    else          { src = gatW + (size_t)(mat - 1) * 65536; tr = false; }
    unsigned short* d = dst + ((size_t)mat * 16384 + r) * 16;
    if (ks < 8) {
        #pragma unroll
        for (int j = 0; j < 8; j++) {
            float v = tr ? src[n * 256 + k0 + j] : src[(size_t)(k0 + j) * 256 + n];
            unsigned short hi = f2bf(v);
            d[j]     = hi;
            d[8 + j] = f2bf(v - bf2f(hi));
        }
    } else {
        #pragma unroll
        for (int j = 0; j < 8; j++) { d[j] = 0; d[8 + j] = 0; }
    }
}

// ---------------------------------------------------------------------------
// Fully fused GNN: in_proj + 3 GAT layers + masked frame mean.
// 1024 threads = 16 waves per (b,t) block -> 4 waves/SIMD between barriers.
// Round-2 memory plan (x planes + hT both resident, residual read at phase F)
// but per-wave work halved: wave w owns ONE 16-channel nt tile in B/C
// (acc[4] = 16 regs) and one (head = w>>2, d-quarter = w&3) tile in E/F
// (macc[4] = 16 regs). Peak live regs ~80 << 128 cap -> no scratch spill.
__global__ __launch_bounds__(1024, 4) void k_gnn(const float* __restrict__ feats,
                                                 const float* __restrict__ boxes,
                                                 const float* __restrict__ maskp,
                                                 const unsigned short* __restrict__ BswAll,
                                                 const float* __restrict__ inb,
                                                 const float* __restrict__ edgeW,
                                                 const float* __restrict__ attSg,
                                                 const float* __restrict__ attDg,
                                                 const float* __restrict__ attEg,
                                                 const float* __restrict__ gbias,
                                                 const float* __restrict__ glns,
                                                 const float* __restrict__ glnb,
                                                 float* __restrict__ framebuf) {
    int bt = blockIdx.x;
    size_t fbase = (size_t)bt * 64 * 256;

    __shared__ unsigned short xH[64 * XP];       // x hi plane (also feats staging)
    __shared__ unsigned short xL[64 * XP];       // x lo plane
    __shared__ unsigned short hT[256 * 136];     // h bf16 c-major: [c][0..63]=hi,[64..127]=lo
    __shared__ float pxS[64], pyS[64], vmS[64];
    __shared__ float loopS[192];
    __shared__ float asrcS[16][64], adstS[16][64]; // per-WAVE partials (4 waves per head)
    __shared__ float wESall[36];                 // [l][e][h]
    __shared__ float sumsS[64][8];               // [d][head*2 + {sum,sum2}]
    __shared__ float mrsS[64][2];
    __shared__ float nvS;

    int tid = threadIdx.x, lane = tid & 63, w = tid >> 6;   // w 0..15
    int ln15 = lane & 15, q = lane >> 4;
    int nt = w;              // B/C role: 16 output channels c = nt*16+ln15
    int eh = w >> 2;         // E/F role: head
    int dq = w & 3;          // E/F role: d-quarter (16 rows)

    // ---- Phase 0a: geometry + per-layer wES + feats staging (pre-split) ----
    if (tid < 64) {
        const float* bx = boxes + (size_t)(bt * 64 + tid) * 5;
        pxS[tid] = bx[1];
        pyS[tid] = bx[2];
        vmS[tid] = maskp[bt * 64 + tid];
    } else if (tid < 100) {
        int idx = tid - 64;                  // l*12 + e*4 + h2
        int l = idx / 12, r2 = idx - l * 12;
        int e = r2 >> 2, h2 = r2 & 3;
        float sm = 0.f;
        const float* ew = edgeW + (size_t)l * 768 + e * 256 + h2 * 64;
        const float* ae = attEg + (size_t)l * 256 + h2 * 64;
        for (int c = 0; c < 64; c++) sm += ew[c] * ae[c];
        wESall[idx] = sm;
    }
    #pragma unroll
    for (int j = 0; j < 4; j++) {
        int g = j * 4096 + tid * 4;
        int row = g >> 8, col = g & 255;
        float4 v4 = *(const float4*)&feats[fbase + g];
        union { u16x4 v; unsigned short u[4]; } H4, L4;
        float vf[4] = {v4.x, v4.y, v4.z, v4.w};
        #pragma unroll
        for (int jj = 0; jj < 4; jj++) {
            H4.u[jj] = f2bf(vf[jj]);
            L4.u[jj] = f2bf(vf[jj] - bf2f(H4.u[jj]));
        }
        *(u16x4*)&xH[row * XP + col] = H4.v;
        *(u16x4*)&xL[row * XP + col] = L4.v;
    }
    __syncthreads();

    // ---- Phase 0b: self-loop edge-attr averages + nvalid ----
    {
        int d = tid >> 4, part = tid & 15;
        float pxd = pxS[d], pyd = pyS[d];
        bool vd = vmS[d] > 0.5f;
        float deg = 0.f, s0 = 0.f, s1 = 0.f, s2 = 0.f;
        #pragma unroll
        for (int k = 0; k < 4; k++) {
            int s = part * 4 + k;
            float rx = pxd - pxS[s], ry = pyd - pyS[s];
            float dist = sqrtf(fmaxf(rx * rx + ry * ry, 1e-12f));
            bool adj = vd && (vmS[s] > 0.5f) && (dist < 0.3f) && (s != d);
            if (adj) { deg += 1.f; s0 += dist; s1 += rx; s2 += ry; }
        }
        #pragma unroll
        for (int off = 1; off < 16; off <<= 1) {
            deg += __shfl_xor(deg, off);
            s0  += __shfl_xor(s0, off);
            s1  += __shfl_xor(s1, off);
            s2  += __shfl_xor(s2, off);
        }
        if (part == 0) {
            float dg = fmaxf(deg, 1.f);
            loopS[d * 3 + 0] = s0 / dg;
            loopS[d * 3 + 1] = s1 / dg;
            loopS[d * 3 + 2] = s2 / dg;
        }
    }
    if (tid == 0) {
        float nv = 0.f;
        for (int m = 0; m < 64; m++) nv += vmS[m] > 0.5f ? 1.f : 0.f;
        nvS = fmaxf(nv, 1.f);
    }

    // ---- Phase 0c: in_proj MFMA (A = staged feats in xH/xL, B = Bsw mat 0) ----
    {
        f32x4 acc[4];
        #pragma unroll
        for (int mt = 0; mt < 4; mt++) acc[mt] = (f32x4){0.f, 0.f, 0.f, 0.f};
        for (int ks = 0; ks < 8; ks++) {
            const unsigned short* fb = &BswAll[((size_t)(ks * 16 + nt) * 64 + lane) * 16];
            bf16x8 bhi = *(const bf16x8*)&fb[0];
            bf16x8 blo = *(const bf16x8*)&fb[8];
            #pragma unroll
            for (int mt = 0; mt < 4; mt++) {
                int ao = (mt * 16 + ln15) * XP + ks * 32 + q * 8;
                bf16x8 ahi = *(const bf16x8*)&xH[ao];
                bf16x8 alo = *(const bf16x8*)&xL[ao];
                acc[mt] = __builtin_amdgcn_mfma_f32_16x16x32_bf16(ahi, bhi, acc[mt], 0, 0, 0);
                acc[mt] = __builtin_amdgcn_mfma_f32_16x16x32_bf16(alo, bhi, acc[mt], 0, 0, 0);
                acc[mt] = __builtin_amdgcn_mfma_f32_16x16x32_bf16(ahi, blo, acc[mt], 0, 0, 0);
            }
        }
        __syncthreads();   // all feats reads done; safe to overwrite with x
        int c = nt * 16 + ln15;
        float bv = inb[c];
        #pragma unroll
        for (int mt = 0; mt < 4; mt++) {
            #pragma unroll
            for (int r = 0; r < 4; r++) {
                int m = mt * 16 + q * 4 + r;
                float v = (acc[mt][r] + bv) * (vmS[m] > 0.5f ? 1.f : 0.f);
                unsigned short hi = f2bf(v);
                xH[m * XP + c] = hi;
                xL[m * XP + c] = f2bf(v - bf2f(hi));
            }
        }
    }
    __syncthreads();

    // ---- 3 GAT layers, x resident in LDS ----
    for (int l = 0; l < 3; l++) {
        const unsigned short* BswL = BswAll + (size_t)(1 + l) * 16384 * 16;
        const float* attSl = attSg + (size_t)l * 256;
        const float* attDl = attDg + (size_t)l * 256;
        const float* biasl = gbias + (size_t)l * 256;
        const float* lnsl  = glns + (size_t)l * 256;
        const float* lnbl  = glnb + (size_t)l * 256;
        const float* wES   = wESall + l * 12;

        // Phase B: h = x @ W (wave owns nt tile: 64 rows x 16 channels)
        f32x4 acc[4];
        #pragma unroll
        for (int mt = 0; mt < 4; mt++) acc[mt] = (f32x4){0.f, 0.f, 0.f, 0.f};
        for (int ks = 0; ks < 8; ks++) {
            const unsigned short* fb = &BswL[((size_t)(ks * 16 + nt) * 64 + lane) * 16];
            bf16x8 bhi = *(const bf16x8*)&fb[0];
            bf16x8 blo = *(const bf16x8*)&fb[8];
            #pragma unroll
            for (int mt = 0; mt < 4; mt++) {
                int ao = (mt * 16 + ln15) * XP + ks * 32 + q * 8;
                bf16x8 ahi = *(const bf16x8*)&xH[ao];
                bf16x8 alo = *(const bf16x8*)&xL[ao];
                acc[mt] = __builtin_amdgcn_mfma_f32_16x16x32_bf16(ahi, bhi, acc[mt], 0, 0, 0);
                acc[mt] = __builtin_amdgcn_mfma_f32_16x16x32_bf16(alo, bhi, acc[mt], 0, 0, 0);
                acc[mt] = __builtin_amdgcn_mfma_f32_16x16x32_bf16(ahi, blo, acc[mt], 0, 0, 0);
            }
        }

        // Phase C: h -> hT (packed u16x4 stores) + per-wave a_src/a_dst partials.
        {
            int c = nt * 16 + ln15;
            float aS = attSl[c], aD = attDl[c];
            float pS[4][4], pD[4][4];
            #pragma unroll
            for (int mt = 0; mt < 4; mt++) {
                union { u16x4 v; unsigned short u[4]; } HH, LL;
                #pragma unroll
                for (int r = 0; r < 4; r++) {
                    float v = acc[mt][r];
                    pS[mt][r] = v * aS;
                    pD[mt][r] = v * aD;
                    unsigned short hi = f2bf(v);
                    HH.u[r] = hi;
                    LL.u[r] = f2bf(v - bf2f(hi));
                }
                int s = mt * 16 + q * 4;
                *(u16x4*)&hT[c * 136 + s] = HH.v;
                *(u16x4*)&hT[c * 136 + 64 + s] = LL.v;
            }
            #pragma unroll
            for (int off = 1; off < 16; off <<= 1) {
                #pragma unroll
                for (int mt = 0; mt < 4; mt++)
                    #pragma unroll
                    for (int r = 0; r < 4; r++) {
                        pS[mt][r] += __shfl_xor(pS[mt][r], off);
                        pD[mt][r] += __shfl_xor(pD[mt][r], off);
                    }
            }
            if (ln15 == 0) {
                #pragma unroll
                for (int mt = 0; mt < 4; mt++)
                    #pragma unroll
                    for (int r = 0; r < 4; r++) {
                        int m = mt * 16 + q * 4 + r;
                        asrcS[w][m] = pS[mt][r];
                        adstS[w][m] = pD[mt][r];
                    }
            }
        }
        __syncthreads();

        // Phase E: wave = (head eh, d-quarter dq). logits -> softmax -> alpha
        // hi/lo A-frags -> P.H MFMA into macc[4].
        f32x4 macc[4];
        #pragma unroll
        for (int ct = 0; ct < 4; ct++) macc[ct] = (f32x4){0.f, 0.f, 0.f, 0.f};
        {
            int d = dq * 16 + ln15;
            float pxd = pxS[d], pyd = pyS[d];
            bool vdv = vmS[d] > 0.5f;
            float adstv = adstS[4 * eh][d] + adstS[4 * eh + 1][d]
                        + adstS[4 * eh + 2][d] + adstS[4 * eh + 3][d];
            float lp0 = loopS[d * 3 + 0];
            float lp1 = loopS[d * 3 + 1];
            float lp2 = loopS[d * 3 + 2];
            float we0 = wES[eh], we1 = wES[4 + eh], we2 = wES[8 + eh];

            float lg[16];
            #pragma unroll
            for (int ks = 0; ks < 2; ks++) {
                int s0 = ks * 32 + q * 8;
                F8 PX, PY, VM, AU;
                PX.v2[0] = *(const float4*)&pxS[s0]; PX.v2[1] = *(const float4*)&pxS[s0 + 4];
                PY.v2[0] = *(const float4*)&pyS[s0]; PY.v2[1] = *(const float4*)&pyS[s0 + 4];
                VM.v2[0] = *(const float4*)&vmS[s0]; VM.v2[1] = *(const float4*)&vmS[s0 + 4];
                AU.v2[0] = *(const float4*)&asrcS[4 * eh][s0];
                AU.v2[1] = *(const float4*)&asrcS[4 * eh][s0 + 4];
                #pragma unroll
                for (int i = 1; i < 4; i++) {
                    float4 a0 = *(const float4*)&asrcS[4 * eh + i][s0];
                    float4 a1 = *(const float4*)&asrcS[4 * eh + i][s0 + 4];
                    AU.v2[0].x += a0.x; AU.v2[0].y += a0.y; AU.v2[0].z += a0.z; AU.v2[0].w += a0.w;
                    AU.v2[1].x += a1.x; AU.v2[1].y += a1.y; AU.v2[1].z += a1.z; AU.v2[1].w += a1.w;
                }
                #pragma unroll
                for (int j = 0; j < 8; j++) {
                    int s = s0 + j;
                    float vsf = VM.f[j];
                    float rx = pxd - PX.f[j], ry = pyd - PY.f[j];
                    float dist = sqrtf(fmaxf(rx * rx + ry * ry, 1e-12f));
                    bool self = (s == d);
                    bool adj = vdv && (vsf > 0.5f) && (dist < 0.3f) && !self;
                    float e0 = adj ? dist : (self ? lp0 : 0.f);
                    float e1 = adj ? rx   : (self ? lp1 : 0.f);
                    float e2 = adj ? ry   : (self ? lp2 : 0.f);
                    bool fa = adj || (self && vdv);
                    float lv = AU.f[j] + adstv + e0 * we0 + e1 * we1 + e2 * we2;
                    lv = lv >= 0.f ? lv : 0.2f * lv;
                    lg[ks * 8 + j] = fa ? lv : -1e9f;
                }
            }

            // softmax over s (in-lane 16 + xor16/xor32 over q)
            float mx = lg[0];
            #pragma unroll
            for (int j = 1; j < 16; j++) mx = fmaxf(mx, lg[j]);
            mx = fmaxf(mx, __shfl_xor(mx, 16));
            mx = fmaxf(mx, __shfl_xor(mx, 32));
            float sm = 0.f;
            #pragma unroll
            for (int j = 0; j < 16; j++) { lg[j] = __expf(lg[j] - mx); sm += lg[j]; }
            sm += __shfl_xor(sm, 16);
            sm += __shfl_xor(sm, 32);
            float inv = 1.f / sm;

            bf16x8 ah[2], al[2];
            #pragma unroll
            for (int ks2 = 0; ks2 < 2; ks2++) {
                union { bf16x8 v; unsigned short u[8]; } H, L;
                #pragma unroll
                for (int j = 0; j < 8; j++) {
                    float a = lg[ks2 * 8 + j] * inv;
                    unsigned short hi = f2bf(a);
                    H.u[j] = hi;
                    L.u[j] = f2bf(a - bf2f(hi));
                }
                ah[ks2] = H.v; al[ks2] = L.v;
            }

            // P.H MFMA: msg[d][c] for d in dq*16..+16, c in eh*64..+64
            #pragma unroll
            for (int ks2 = 0; ks2 < 2; ks2++) {
                #pragma unroll
                for (int ct = 0; ct < 4; ct++) {
                    const unsigned short* hb =
                        &hT[(size_t)(eh * 64 + ct * 16 + ln15) * 136 + ks2 * 32 + q * 8];
                    bf16x8 bhi = *(const bf16x8*)&hb[0];
                    bf16x8 blo = *(const bf16x8*)&hb[64];
                    macc[ct] = __builtin_amdgcn_mfma_f32_16x16x32_bf16(ah[ks2], bhi, macc[ct], 0, 0, 0);
                    macc[ct] = __builtin_amdgcn_mfma_f32_16x16x32_bf16(al[ks2], bhi, macc[ct], 0, 0, 0);
                    macc[ct] = __builtin_amdgcn_mfma_f32_16x16x32_bf16(ah[ks2], blo, macc[ct], 0, 0, 0);
                }
            }
        }

        // Phase F: LN(msg + bias + x_old) + relu, write new x (x planes still live).
        {
            float bsv[4], scv[4], bbv[4];
            #pragma unroll
            for (int ct = 0; ct < 4; ct++) {
                int c = eh * 64 + ct * 16 + ln15;
                bsv[ct] = biasl[c];
                scv[ct] = lnsl[c];
                bbv[ct] = lnbl[c];
            }
            float xo[4][4];
            #pragma unroll
            for (int r = 0; r < 4; r++) {
                int d2 = dq * 16 + q * 4 + r;
                #pragma unroll
                for (int ct = 0; ct < 4; ct++) {
                    int o = d2 * XP + eh * 64 + ct * 16 + ln15;
                    xo[ct][r] = bf2f(xH[o]) + bf2f(xL[o]);
                }
            }
            float ps[4], ps2[4];
            #pragma unroll
            for (int r = 0; r < 4; r++) {
                float s = 0.f, s2 = 0.f;
                #pragma unroll
                for (int ct = 0; ct < 4; ct++) {
                    float v = macc[ct][r] + xo[ct][r] + bsv[ct];
                    s += v; s2 += v * v;
                }
                ps[r] = s; ps2[r] = s2;
            }
            #pragma unroll
            for (int off = 1; off < 16; off <<= 1) {
                #pragma unroll
                for (int i = 0; i < 4; i++) {
                    ps[i]  += __shfl_xor(ps[i], off);
                    ps2[i] += __shfl_xor(ps2[i], off);
                }
            }
            if (ln15 == 0) {
                #pragma unroll
                for (int r = 0; r < 4; r++) {
                    int d2 = dq * 16 + q * 4 + r;
                    sumsS[d2][eh * 2 + 0] = ps[r];
                    sumsS[d2][eh * 2 + 1] = ps2[r];
                }
            }
            __syncthreads();
            if (tid < 64) {
                float S  = sumsS[tid][0] + sumsS[tid][2] + sumsS[tid][4] + sumsS[tid][6];
                float S2 = sumsS[tid][1] + sumsS[tid][3] + sumsS[tid][5] + sumsS[tid][7];
                float mu = S * (1.f / 256.f);
                float var = S2 * (1.f / 256.f) - mu * mu;
                mrsS[tid][0] = mu;
                mrsS[tid][1] = rsqrtf(var + 1e-5f);
            }
            __syncthreads();
            #pragma unroll
            for (int r = 0; r < 4; r++) {
                int d2 = dq * 16 + q * 4 + r;
                float mu = mrsS[d2][0], rs = mrsS[d2][1];
                #pragma unroll
                for (int ct = 0; ct < 4; ct++) {
                    float v = (macc[ct][r] + xo[ct][r] + bsv[ct] - mu) * rs * scv[ct] + bbv[ct];
                    v = fmaxf(v, 0.f);
                    unsigned short hi = f2bf(v);
                    int o = d2 * XP + eh * 64 + ct * 16 + ln15;
                    xH[o] = hi;
                    xL[o] = f2bf(v - bf2f(hi));
                }
            }
        }
        __syncthreads();   // x ready for next layer / frame mean
    }

    // ---- masked frame mean -> framebuf ----
    if (tid < 256) {
        float s = 0.f;
        for (int m = 0; m < 64; m++) {
            float xv = bf2f(xH[m * XP + tid]) + bf2f(xL[m * XP + tid]);
            s += xv * (vmS[m] > 0.5f ? 1.f : 0.f);
        }
        framebuf[(size_t)bt * 256 + tid] = s / nvS;
    }
}

// ---------------------------------------------------------------------------
// temp proj from precomputed frame means, 4 tokens per block
__global__ __launch_bounds__(256) void k_temp4(const float* __restrict__ framebuf,
                                               const float* __restrict__ tW,
                                               const float* __restrict__ tb,
                                               const float* __restrict__ pe,
                                               float* __restrict__ ybuf) {
    int b4 = blockIdx.x;   // 0..511
    int tid = threadIdx.x;
    __shared__ float frS[4][256];
    #pragma unroll
    for (int t = 0; t < 4; t++) frS[t][tid] = framebuf[(size_t)(b4 * 4 + t) * 256 + tid];
    __syncthreads();
    float acc[4];
    #pragma unroll
    for (int t = 0; t < 4; t++) acc[t] = tb[tid] + pe[((b4 * 4 + t) & 31) * 256 + tid];
    const float* wrow = tW + (size_t)tid * 256;
    for (int g = 0; g < 256; g += 4) {
        float4 wv = *(const float4*)&wrow[g];
        #pragma unroll
        for (int t = 0; t < 4; t++) acc[t] += dot4(*(const float4*)&frS[t][g], wv);
    }
    #pragma unroll
    for (int t = 0; t < 4; t++) ybuf[(size_t)(b4 * 4 + t) * 256 + tid] = acc[t];
}

// ---------------------------------------------------------------------------
// LN1 + qkv, 4 tokens per block; wave-per-token LN.
__global__ __launch_bounds__(256) void k_ln_qkv4(const float* __restrict__ ybuf,
                                                 const float* __restrict__ ln_s,
                                                 const float* __restrict__ ln_b,
                                                 const float* __restrict__ qW,
                                                 const float* __restrict__ qb,
                                                 float* __restrict__ qkvbuf) {
    int b4 = blockIdx.x, tid = threadIdx.x;
    int lane = tid & 63, wv = tid >> 6;
    __shared__ float zS[4][256];
    {
        int bt = b4 * 4 + wv;
        float4 yv = *(const float4*)&ybuf[(size_t)bt * 256 + lane * 4];
        float s = yv.x + yv.y + yv.z + yv.w;
        float s2 = yv.x * yv.x + yv.y * yv.y + yv.z * yv.z + yv.w * yv.w;
        #pragma unroll
        for (int off = 1; off < 64; off <<= 1) { s += __shfl_xor(s, off); s2 += __shfl_xor(s2, off); }
        float mu = s * (1.f / 256.f);
        float var = s2 * (1.f / 256.f) - mu * mu;
        float rstd = rsqrtf(var + 1e-5f);
        float4 ls = *(const float4*)&ln_s[lane * 4];
        float4 lb = *(const float4*)&ln_b[lane * 4];
        float4 z;
        z.x = (yv.x - mu) * rstd * ls.x + lb.x;
        z.y = (yv.y - mu) * rstd * ls.y + lb.y;
        z.z = (yv.z - mu) * rstd * ls.z + lb.z;
        z.w = (yv.w - mu) * rstd * ls.w + lb.w;
        *(float4*)&zS[wv][lane * 4] = z;
    }
    __syncthreads();
    for (int r = 0; r < 3; r++) {
        int j = r * 256 + tid;
        float acc[4];
        float bv = qb[j];
        #pragma unroll
        for (int t = 0; t < 4; t++) acc[t] = bv;
        const float* wrow = qW + (size_t)j * 256;
        for (int i = 0; i < 256; i += 4) {
            float4 wv4 = *(const float4*)&wrow[i];
            #pragma unroll
            for (int t = 0; t < 4; t++) acc[t] += dot4(*(const float4*)&zS[t][i], wv4);
        }
        #pragma unroll
        for (int t = 0; t < 4; t++) qkvbuf[(size_t)(b4 * 4 + t) * 768 + j] = acc[t];
    }
}

// ---------------------------------------------------------------------------
__global__ __launch_bounds__(64) void k_attn(const float* __restrict__ qkvbuf,
                                             float* __restrict__ obuf) {
    int blk = blockIdx.x;
    int b = blk >> 3, h = blk & 7;
    int tid = threadIdx.x;
    __shared__ float Ks[32 * 32], Vs[32 * 32];
    for (int idx = tid; idx < 1024; idx += 64) {
        int tk = idx >> 5, c = idx & 31;
        size_t qbase = ((size_t)(b * 32 + tk)) * 768 + h * 32 + c;
        Ks[idx] = qkvbuf[qbase + 256];
        Vs[idx] = qkvbuf[qbase + 512];
    }
    __syncthreads();
    if (tid < 32) {
        int tq = tid;
        float qv[32];
        size_t qb0 = ((size_t)(b * 32 + tq)) * 768 + h * 32;
        #pragma unroll
        for (int c = 0; c < 32; c++) qv[c] = qkvbuf[qb0 + c];
        float scr[32];
        float mx = -1e30f;
        #pragma unroll
        for (int tk = 0; tk < 32; tk++) {
            float dd = 0.f;
            #pragma unroll
            for (int c = 0; c < 32; c++) dd = fmaf(qv[c], Ks[tk * 32 + c], dd);
            dd *= 0.17677669529663687f;
            scr[tk] = dd;
            mx = fmaxf(mx, dd);
        }
        float sm = 0.f;
        #pragma unroll
        for (int tk = 0; tk < 32; tk++) { scr[tk] = __expf(scr[tk] - mx); sm += scr[tk]; }
        float inv = 1.f / sm;
        float o[32];
        #pragma unroll
        for (int c = 0; c < 32; c++) o[c] = 0.f;
        #pragma unroll
        for (int tk = 0; tk < 32; tk++) {
            float a = scr[tk] * inv;
            #pragma unroll
            for (int c = 0; c < 32; c++) o[c] = fmaf(a, Vs[tk * 32 + c], o[c]);
        }
        size_t ob = ((size_t)(b * 32 + tq)) * 256 + h * 32;
        #pragma unroll
        for (int c = 0; c < 32; c++) obuf[ob + c] = o[c];
    }
}

// ---------------------------------------------------------------------------
__global__ __launch_bounds__(256) void k_attn_out4(const float* __restrict__ obuf,
                                                   const float* __restrict__ W,
                                                   const float* __restrict__ bvec,
                                                   float* __restrict__ ybuf) {
    int b4 = blockIdx.x, tid = threadIdx.x;
    int lane = tid & 63, wv = tid >> 6;
    __shared__ float oS[4][256];
    *(float4*)&oS[wv][lane * 4] = *(const float4*)&obuf[(size_t)(b4 * 4 + wv) * 256 + lane * 4];
    __syncthreads();
    float acc[4];
    float bv = bvec[tid];
    #pragma unroll
    for (int t = 0; t < 4; t++) acc[t] = bv;
    const float* wrow = W + (size_t)tid * 256;
    for (int i = 0; i < 256; i += 4) {
        float4 wv4 = *(const float4*)&wrow[i];
        #pragma unroll
        for (int t = 0; t < 4; t++) acc[t] += dot4(*(const float4*)&oS[t][i], wv4);
    }
    #pragma unroll
    for (int t = 0; t < 4; t++) ybuf[(size_t)(b4 * 4 + t) * 256 + tid] += acc[t];
}

// ---------------------------------------------------------------------------
__global__ __launch_bounds__(256) void k_ff4(float* __restrict__ ybuf,
                                             const float* __restrict__ ln_s,
                                             const float* __restrict__ ln_b,
                                             const float* __restrict__ W1,
                                             const float* __restrict__ b1,
                                             const float* __restrict__ W2,
                                             const float* __restrict__ b2) {
    int b4 = blockIdx.x, tid = threadIdx.x;
    int lane = tid & 63, wv = tid >> 6;
    __shared__ float zS[4][256];
    __shared__ float fS[4][512];
    {
        int bt = b4 * 4 + wv;
        float4 yv = *(const float4*)&ybuf[(size_t)bt * 256 + lane * 4];
        float s = yv.x + yv.y + yv.z + yv.w;
        float s2 = yv.x * yv.x + yv.y * yv.y + yv.z * yv.z + yv.w * yv.w;
        #pragma unroll
        for (int off = 1; off < 64; off <<= 1) { s += __shfl_xor(s, off); s2 += __shfl_xor(s2, off); }
        float mu = s * (1.f / 256.f);
        float var = s2 * (1.f / 256.f) - mu * mu;
        float rstd = rsqrtf(var + 1e-5f);
        float4 ls = *(const float4*)&ln_s[lane * 4];
        float4 lb = *(const float4*)&ln_b[lane * 4];
        float4 z;
        z.x = (yv.x - mu) * rstd * ls.x + lb.x;
        z.y = (yv.y - mu) * rstd * ls.y + lb.y;
        z.z = (yv.z - mu) * rstd * ls.z + lb.z;
        z.w = (yv.w - mu) * rstd * ls.w + lb.w;
        *(float4*)&zS[wv][lane * 4] = z;
    }
    __syncthreads();
    for (int r = 0; r < 2; r++) {
        int j = r * 256 + tid;
        float acc[4];
        float bv = b1[j];
        #pragma unroll
        for (int t = 0; t < 4; t++) acc[t] = bv;
        const float* wrow = W1 + (size_t)j * 256;
        for (int i = 0; i < 256; i += 4) {
            float4 wv4 = *(const float4*)&wrow[i];
            #pragma unroll
            for (int t = 0; t < 4; t++) acc[t] += dot4(*(const float4*)&zS[t][i], wv4);
        }
        #pragma unroll
        for (int t = 0; t < 4; t++) fS[t][j] = fmaxf(acc[t], 0.f);
    }
    __syncthreads();
    float acc[4];
    float bv = b2[tid];
    #pragma unroll
    for (int t = 0; t < 4; t++) acc[t] = bv;
    const float* wrow = W2 + (size_t)tid * 512;
    for (int jj = 0; jj < 512; jj += 4) {
        float4 wv4 = *(const float4*)&wrow[jj];
        #pragma unroll
        for (int t = 0; t < 4; t++) acc[t] += dot4(*(const float4*)&fS[t][jj], wv4);
    }
    #pragma unroll
    for (int t = 0; t < 4; t++) {
        size_t idx = (size_t)(b4 * 4 + t) * 256 + tid;
        ybuf[idx] = ybuf[idx] + acc[t];
    }
}

// ---------------------------------------------------------------------------
__global__ __launch_bounds__(256) void k_pool_out(const float* __restrict__ ybuf,
                                                  const float* __restrict__ pW,
                                                  const float* __restrict__ pb,
                                                  const float* __restrict__ oW,
                                                  const float* __restrict__ ob,
                                                  const float* __restrict__ lns,
                                                  const float* __restrict__ lnb,
                                                  float* __restrict__ dout) {
    int b = blockIdx.x, tid = threadIdx.x;
    __shared__ float redP[256];
    __shared__ float wS[32];
    __shared__ float pS[256];
    __shared__ float red[8];
    int tq = tid >> 3, part = tid & 7;
    float partial = 0.f;
    {
        const float* yrow = ybuf + ((size_t)(b * 32 + tq)) * 256 + part * 32;
        const float* pwp = pW + part * 32;
        #pragma unroll
        for (int j = 0; j < 32; j += 4) {
            float4 yv = *(const float4*)&yrow[j];
            float4 wv = *(const float4*)&pwp[j];
            partial += dot4(yv, wv);
        }
    }
    redP[tid] = partial;
    __syncthreads();
    if (tid < 32) {
        float s = pb[0];
        for (int p = 0; p < 8; p++) s += redP[tid * 8 + p];
        float mx = s;
        #pragma unroll
        for (int off = 16; off; off >>= 1) mx = fmaxf(mx, __shfl_xor(mx, off));
        float e = __expf(s - mx);
        float sm = e;
        #pragma unroll
        for (int off = 16; off; off >>= 1) sm += __shfl_xor(sm, off);
        wS[tid] = e / sm;
    }
    __syncthreads();
    float p = 0.f;
    for (int t = 0; t < 32; t++) p += ybuf[((size_t)(b * 32 + t)) * 256 + tid] * wS[t];
    pS[tid] = p;
    __syncthreads();
    float accs[2];
    for (int r = 0; r < 2; r++) {
        int j = r * 256 + tid;
        float acc = ob[j];
        const float* wrow = oW + (size_t)j * 256;
        for (int g = 0; g < 256; g += 4) {
            float4 pv = *(const float4*)&pS[g];
            float4 wv = *(const float4*)&wrow[g];
            acc += dot4(pv, wv);
        }
        accs[r] = acc;
    }
    float s = accs[0] + accs[1];
    float s2 = accs[0] * accs[0] + accs[1] * accs[1];
    #pragma unroll
    for (int off = 32; off; off >>= 1) {
        s += __shfl_xor(s, off);
        s2 += __shfl_xor(s2, off);
    }
    int wid = threadIdx.x >> 6;
    int lane = threadIdx.x & 63;
    if (lane == 0) { red[wid] = s; red[4 + wid] = s2; }
    __syncthreads();
    s = red[0] + red[1] + red[2] + red[3];
    s2 = red[4] + red[5] + red[6] + red[7];
    float mu = s * (1.f / 512.f);
    float var = s2 * (1.f / 512.f) - mu * mu;
    float rstd = rsqrtf(var + 1e-5f);
    dout[b * 512 + tid]       = fmaxf((accs[0] - mu) * rstd * lns[tid] + lnb[tid], 0.f);
    dout[b * 512 + tid + 256] = fmaxf((accs[1] - mu) * rstd * lns[tid + 256] + lnb[tid + 256], 0.f);
}

// ---------------------------------------------------------------------------
extern "C" void kernel_launch(void* const* d_in, const int* in_sizes, int n_in,
                              void* d_out, int out_size, void* d_ws, size_t ws_size,
                              hipStream_t stream) {
    const float* drone_feats = (const float*)d_in[0];
    const float* boxes       = (const float*)d_in[1];
    const float* drone_mask  = (const float*)d_in[2];
    const float* in_proj_W   = (const float*)d_in[3];
    const float* in_proj_b   = (const float*)d_in[4];
    const float* gat_lin_W   = (const float*)d_in[5];
    const float* gat_edge_W  = (const float*)d_in[6];
    const float* gat_att_src = (const float*)d_in[7];
    const float* gat_att_dst = (const float*)d_in[8];
    const float* gat_att_edge= (const float*)d_in[9];
    const float* gat_bias    = (const float*)d_in[10];
    const float* gat_ln_s    = (const float*)d_in[11];
    const float* gat_ln_b    = (const float*)d_in[12];
    const float* temp_W      = (const float*)d_in[13];
    const float* temp_b      = (const float*)d_in[14];
    const float* pos_emb     = (const float*)d_in[15];
    const float* qkv_W       = (const float*)d_in[16];
    const float* qkv_b       = (const float*)d_in[17];
    const float* attn_out_W  = (const float*)d_in[18];
    const float* attn_out_b  = (const float*)d_in[19];
    const float* ln1_s       = (const float*)d_in[20];
    const float* ln1_b       = (const float*)d_in[21];
    const float* ln2_s       = (const float*)d_in[22];
    const float* ln2_b       = (const float*)d_in[23];
    const float* ff1_W       = (const float*)d_in[24];
    const float* ff1_b       = (const float*)d_in[25];
    const float* ff2_W       = (const float*)d_in[26];
    const float* ff2_b       = (const float*)d_in[27];
    const float* pool_W      = (const float*)d_in[28];
    const float* pool_b      = (const float*)d_in[29];
    const float* out_W       = (const float*)d_in[30];
    const float* out_b       = (const float*)d_in[31];
    const float* out_ln_s    = (const float*)d_in[32];
    const float* out_ln_b    = (const float*)d_in[33];
    float* out = (float*)d_out;

    float* ws = (float*)d_ws;
    unsigned short* Bsw = (unsigned short*)ws;           // 4*16384*16 ushorts = 2 MB
    size_t off = (size_t)(4 * 16384 * 16) / 2;           // in floats
    float* framebuf = ws + off; off += (size_t)BT * 256;
    float* ybuf   = ws + off; off += (size_t)BT * 256;
    float* qkvbuf = ws + off; off += (size_t)BT * 768;
    float* obuf   = ws + off; off += (size_t)BT * 256;

    k_prep<<<dim3(256), dim3(256), 0, stream>>>(in_proj_W, gat_lin_W, Bsw);
    k_gnn<<<dim3(BT), dim3(1024), 0, stream>>>(drone_feats, boxes, drone_mask, Bsw,
        in_proj_b, gat_edge_W, gat_att_src, gat_att_dst, gat_att_edge,
        gat_bias, gat_ln_s, gat_ln_b, framebuf);
    k_temp4<<<dim3(BT / 4), dim3(256), 0, stream>>>(framebuf, temp_W, temp_b, pos_emb, ybuf);
    for (int l = 0; l < 2; l++) {
        k_ln_qkv4<<<dim3(BT / 4), dim3(256), 0, stream>>>(ybuf, ln1_s + l * 256, ln1_b + l * 256,
            qkv_W + (size_t)l * 768 * 256, qkv_b + l * 768, qkvbuf);
        k_attn<<<dim3(512), dim3(64), 0, stream>>>(qkvbuf, obuf);
        k_attn_out4<<<dim3(BT / 4), dim3(256), 0, stream>>>(obuf,
            attn_out_W + (size_t)l * 65536, attn_out_b + l * 256, ybuf);
        k_ff4<<<dim3(BT / 4), dim3(256), 0, stream>>>(ybuf, ln2_s + l * 256, ln2_b + l * 256,
            ff1_W + (size_t)l * 131072, ff1_b + l * 512,
            ff2_W + (size_t)l * 131072, ff2_b + l * 256);
    }
    k_pool_out<<<dim3(64), dim3(256), 0, stream>>>(ybuf, pool_W, pool_b, out_W, out_b,
                                                   out_ln_s, out_ln_b, out);
}